// Round 4
// baseline (460.443 us; speedup 1.0000x reference)
//
#include <hip/hip_runtime.h>
#include <hip/hip_bf16.h>
#include <stdint.h>

#define NCAT 32
#define DIN  1536
#define DMID 1024
#define NB   128
#define TT   32

#define BM 128
#define BN 64
#define BK 32
#define LDA 40   // ushort stride for A tile rows (16B-aligned rows, spreads banks)
#define MAXG 56
#define NTILE 16 // 1024 / BN

typedef __attribute__((ext_vector_type(8))) short short8;
typedef __attribute__((ext_vector_type(4))) float f32x4;

static __device__ __forceinline__ unsigned int pk2bf(float lo, float hi) {
  unsigned short a = __builtin_bit_cast(unsigned short, __float2bfloat16(lo));
  unsigned short b = __builtin_bit_cast(unsigned short, __float2bfloat16(hi));
  return ((unsigned int)b << 16) | (unsigned int)a;
}

// lgkmcnt(0) only; vmcnt/expcnt left free -> no W-stream drain at barriers.
static __device__ __forceinline__ void pipe_barrier() {
  __builtin_amdgcn_s_waitcnt(0xc07f);
  __builtin_amdgcn_s_barrier();
}

// ws int layout: [0..127] batch_list sorted by category; [128] num_groups;
// [132 + 4g ..] = {cat, start, cnt, pad}.
// byte 8192: x bf16 (12582912 B). byte 8192+12582912: hidden bf16 (8388608 B).
__global__ void build_groups(const int* __restrict__ cat_ids, int* __restrict__ wsi) {
  __shared__ int cats[NB];
  __shared__ int cnt[NCAT];
  __shared__ int off[NCAT];
  int t = threadIdx.x; // blockDim = 128
  cats[t] = cat_ids[t];
  __syncthreads();
  if (t < NCAT) {
    int n = 0;
    for (int b = 0; b < NB; b++) n += (cats[b] == t);
    cnt[t] = n;
  }
  __syncthreads();
  if (t == 0) {
    int acc = 0;
    for (int c = 0; c < NCAT; c++) { off[c] = acc; acc += cnt[c]; }
  }
  __syncthreads();
  if (t < NCAT) {
    int o = off[t];
    for (int b = 0; b < NB; b++)
      if (cats[b] == t) wsi[o++] = b;
  }
  if (t == 0) {
    int g = 0;
    for (int c = 0; c < NCAT; c++) {
      int n = cnt[c], o = off[c];
      for (int j = 0; j < n; j += 4) {
        wsi[132 + g * 4 + 0] = c;
        wsi[132 + g * 4 + 1] = o + j;
        wsi[132 + g * 4 + 2] = (n - j) < 4 ? (n - j) : 4;
        g++;
      }
    }
    wsi[128] = g;
  }
}

// x fp32 -> bf16; 3072 blocks * 256 thr * 8 elems
__global__ void cvt_x_bf16(const float* __restrict__ in, unsigned short* __restrict__ out) {
  int i = blockIdx.x * 256 + threadIdx.x;
  const float4* p = (const float4*)in + (size_t)i * 2;
  float4 a = p[0], b = p[1];
  ((uint4*)out)[i] = make_uint4(pk2bf(a.x, a.y), pk2bf(a.z, a.w),
                                pk2bf(b.x, b.y), pk2bf(b.z, b.w));
}

template <int LAYER>
__global__ __launch_bounds__(256)
void mlp_gemm(const unsigned short* __restrict__ A, const float* __restrict__ W,
              const float* __restrict__ bias, const int* __restrict__ wsi,
              void* __restrict__ Out, int K) {
  // XCD-locality swizzle: n-tiles of a group share id%8.
  const int id = blockIdx.x;
  const int g  = (id & 7) + 8 * (id >> 7);
  const int t  = (id >> 3) & 15;
  if (g >= wsi[128]) return;
  const int cat   = wsi[132 + g * 4 + 0];
  const int start = wsi[132 + g * 4 + 1];
  const int cnt   = wsi[132 + g * 4 + 2];
  const int n0    = t * BN;

  __shared__ unsigned short As[2][BM * LDA];   // 2 x 10240 B
  __shared__ unsigned short Bs[2][4 * BN * 8]; // 2 x 4096 B

  const int tid  = threadIdx.x;
  const int lane = tid & 63;
  const int w    = tid >> 6;

  const int arow  = tid >> 1;
  const int khalf = (tid & 1) * 16;
  const int lb    = arow >> 5;
  const int tok   = arow & 31;
  const int lbc   = lb < (cnt - 1) ? lb : (cnt - 1);
  const int batch = wsi[start + lbc];
  const long grow = (long)(batch * TT + tok);
  const unsigned short* Arow = A + grow * (long)K + khalf;

  const float* Wcol = W + (size_t)cat * (size_t)K * 1024 + n0 + lane;

  f32x4 acc[4][2];
#pragma unroll
  for (int i = 0; i < 4; i++)
#pragma unroll
    for (int j = 0; j < 2; j++) acc[i][j] = (f32x4){0.f, 0.f, 0.f, 0.f};

  const int wm  = (w >> 1) * 64;
  const int wn  = (w & 1) * 32;
  const int kg  = lane >> 4;
  const int c16 = lane & 15;

  const int NT = K / BK;  // 48 (L1) or 32 (L2); both % 4 == 0

  // 4-deep pipeline slots (statically named -> stay in registers)
  uint4 s0_a0, s0_a1, s1_a0, s1_a1, s2_a0, s2_a1, s3_a0, s3_a1;
  float s0_b[8], s1_b[8], s2_b[8], s3_b[8];

#define ISSUE(S, KT) do {                                                  \
    int kk_ = (KT) < NT ? (KT) : (NT - 1);                                 \
    const uint4* ap_ = (const uint4*)(Arow + kk_ * BK);                    \
    S##_a0 = ap_[0]; S##_a1 = ap_[1];                                      \
    const float* bp_ = Wcol + (size_t)(kk_ * BK + w * 8) * 1024;           \
    _Pragma("unroll")                                                      \
    for (int r_ = 0; r_ < 8; r_++) S##_b[r_] = bp_[(size_t)r_ * 1024];     \
  } while (0)

#define STORE(S, BUF) do {                                                 \
    *(uint4*)&As[BUF][arow * LDA + khalf]     = S##_a0;                    \
    *(uint4*)&As[BUF][arow * LDA + khalf + 8] = S##_a1;                    \
    *(uint4*)&Bs[BUF][(w * BN + lane) * 8] = make_uint4(                   \
        pk2bf(S##_b[0], S##_b[1]), pk2bf(S##_b[2], S##_b[3]),              \
        pk2bf(S##_b[4], S##_b[5]), pk2bf(S##_b[6], S##_b[7]));             \
  } while (0)

#define CONSUME(BUF) do {                                                  \
    short8 af_[4], bg_[2];                                                 \
    _Pragma("unroll")                                                      \
    for (int i_ = 0; i_ < 4; i_++)                                         \
      af_[i_] = *(const short8*)&As[BUF][(wm + i_ * 16 + c16) * LDA + kg * 8]; \
    _Pragma("unroll")                                                      \
    for (int j_ = 0; j_ < 2; j_++)                                         \
      bg_[j_] = *(const short8*)&Bs[BUF][(kg * BN + wn + j_ * 16 + c16) * 8];  \
    _Pragma("unroll")                                                      \
    for (int i_ = 0; i_ < 4; i_++)                                         \
      _Pragma("unroll")                                                    \
      for (int j_ = 0; j_ < 2; j_++)                                       \
        acc[i_][j_] = __builtin_amdgcn_mfma_f32_16x16x32_bf16(             \
            af_[i_], bg_[j_], acc[i_][j_], 0, 0, 0);                       \
  } while (0)

  // Prologue: tile0 -> LDS buf0; tiles 1..3 in flight in regs.
  ISSUE(s0, 0);
  ISSUE(s1, 1);
  ISSUE(s2, 2);
  ISSUE(s3, 3);
  STORE(s0, 0);   // waits vmcnt for s0 only; s1..s3 remain outstanding
  pipe_barrier();

  // Steady state: sub-iter T issues tile T+4 (into the slot freed when tile T
  // was stored last sub-iter), consumes LDS tile T, stores tile T+1 (issued
  // 3 sub-iters ago -> ~3 iterations of HBM latency coverage).
  for (int T = 0; T < NT; T += 4) {
    ISSUE(s0, T + 4); CONSUME(0); STORE(s1, 1); pipe_barrier();
    ISSUE(s1, T + 5); CONSUME(1); STORE(s2, 0); pipe_barrier();
    ISSUE(s2, T + 6); CONSUME(0); STORE(s3, 1); pipe_barrier();
    ISSUE(s3, T + 7); CONSUME(1); STORE(s0, 0); pipe_barrier();
  }

#undef ISSUE
#undef STORE
#undef CONSUME

  // ---------- epilogue ----------
  const int rquad = (lane >> 4) * 4;
#pragma unroll
  for (int i = 0; i < 4; i++) {
#pragma unroll
    for (int j = 0; j < 2; j++) {
      int gcol = n0 + wn + j * 16 + c16;
      float bb = bias[cat * 1024 + gcol];
#pragma unroll
      for (int r = 0; r < 4; r++) {
        int lrow = wm + i * 16 + rquad + r;
        int lb2 = lrow >> 5;
        if (lb2 < cnt) {
          int b2 = wsi[start + lb2];
          long orow = (long)(b2 * TT + (lrow & 31));
          float v = acc[i][j][r] + bb;
          if constexpr (LAYER == 1) {
            v = fmaxf(v, 0.f);
            ((unsigned short*)Out)[orow * DMID + gcol] =
                __builtin_bit_cast(unsigned short, __float2bfloat16(v));
          } else {
            ((float*)Out)[orow * 1024 + gcol] = v;
          }
        }
      }
    }
  }
}

extern "C" void kernel_launch(void* const* d_in, const int* in_sizes, int n_in,
                              void* d_out, int out_size, void* d_ws, size_t ws_size,
                              hipStream_t stream) {
  const float* x       = (const float*)d_in[0];
  const int*   cat_ids = (const int*)d_in[1];
  const float* W1      = (const float*)d_in[2];
  const float* b1      = (const float*)d_in[3];
  const float* W2      = (const float*)d_in[4];
  const float* b2      = (const float*)d_in[5];
  float* out = (float*)d_out;

  int* wsi = (int*)d_ws;
  unsigned short* xbf    = (unsigned short*)((char*)d_ws + 8192);
  unsigned short* hidden = (unsigned short*)((char*)d_ws + 8192 + 12582912);

  build_groups<<<dim3(1), dim3(128), 0, stream>>>(cat_ids, wsi);
  cvt_x_bf16<<<dim3(3072), dim3(256), 0, stream>>>(x, xbf);
  mlp_gemm<1><<<dim3(NTILE * MAXG), dim3(256), 0, stream>>>(
      xbf, W1, b1, wsi, (void*)hidden, DIN);
  mlp_gemm<2><<<dim3(NTILE * MAXG), dim3(256), 0, stream>>>(
      hidden, W2, b2, wsi, (void*)out, DMID);
}